// Round 1
// baseline (442.438 us; speedup 1.0000x reference)
//
#include <hip/hip_runtime.h>

#define N_NODES 40000
#define N_EDGES 640000
#define D 128

// ---------------- CSR build ----------------
__global__ void k_count(const int* __restrict__ dst, int* __restrict__ deg) {
  int e = blockIdx.x * 256 + threadIdx.x;
  if (e < N_EDGES) atomicAdd(&deg[dst[e]], 1);
}

// single-block exclusive scan of deg[0..N) -> rs[0..N]
__global__ void k_scan(const int* __restrict__ deg, int* __restrict__ rs) {
  __shared__ int wsum[4];
  __shared__ int carry_s;
  const int tid = threadIdx.x;
  const int lane = tid & 63;
  const int wid = tid >> 6;
  if (tid == 0) carry_s = 0;
  __syncthreads();
  const int CH = 256 * 16;
  for (int base = 0; base < N_NODES; base += CH) {
    int v[16];
    int i0 = base + tid * 16;
    int s = 0;
#pragma unroll
    for (int j = 0; j < 16; ++j) {
      int idx = i0 + j;
      v[j] = (idx < N_NODES) ? deg[idx] : 0;
      s += v[j];
    }
    int sc = s;
#pragma unroll
    for (int d = 1; d < 64; d <<= 1) {
      int t = __shfl_up(sc, d, 64);
      if (lane >= d) sc += t;
    }
    if (lane == 63) wsum[wid] = sc;
    __syncthreads();
    int wpre = 0;
    for (int w = 0; w < wid; ++w) wpre += wsum[w];
    int run = carry_s + wpre + (sc - s);
#pragma unroll
    for (int j = 0; j < 16; ++j) {
      int idx = i0 + j;
      if (idx < N_NODES) rs[idx] = run;
      run += v[j];
    }
    __syncthreads();
    if (tid == 0) carry_s += wsum[0] + wsum[1] + wsum[2] + wsum[3];
    __syncthreads();
  }
  if (tid == 0) rs[N_NODES] = carry_s;
}

__global__ void k_fill(const int* __restrict__ src, const int* __restrict__ dst,
                       const int* __restrict__ rs, int* __restrict__ cursor,
                       int* __restrict__ eidx) {
  int e = blockIdx.x * 256 + threadIdx.x;
  if (e < N_EDGES) {
    int d = dst[e];
    int pos = atomicAdd(&cursor[d], 1);
    eidx[rs[d] + pos] = src[e];
  }
}

// ---------------- aggregation: msg[n] = sum_{e: dst=n} feat[src[e]] ----------------
__global__ void k_aggregate(const float* __restrict__ feat, const int* __restrict__ rs,
                            const int* __restrict__ eidx, float* __restrict__ msg) {
  int w = blockIdx.x * 4 + (threadIdx.x >> 6);   // one wave per node
  int lane = threadIdx.x & 63;
  if (w >= N_NODES) return;
  int beg = rs[w], end = rs[w + 1];
  const float2* f2 = (const float2*)feat;
  float2 acc = make_float2(0.f, 0.f);
  for (int e = beg; e < end; ++e) {
    int s = eidx[e];                              // wave-uniform
    float2 v = f2[(size_t)s * 64 + lane];         // coalesced 512B row read
    acc.x += v.x; acc.y += v.y;
  }
  ((float2*)msg)[(size_t)w * 64 + lane] = acc;
}

// ---------------- fused dual GEMM: out = (msg*inv_deg)@Wl^T + b + xin@Wr^T ----------------
__global__ __launch_bounds__(256) void k_gemm(
    const float* __restrict__ msg, const float* __restrict__ xin,
    const float* __restrict__ Wl, const float* __restrict__ Wr,
    const float* __restrict__ bias, const int* __restrict__ rs,
    float* __restrict__ outp, int relu) {
  __shared__ float sA1[16][128];
  __shared__ float sA2[16][128];
  __shared__ float sW1[32][129];   // +1 pad: conflict-free transpose
  __shared__ float sW2[32][129];
  __shared__ float sScale[16];
  const int tid = threadIdx.x;
  const int n0 = blockIdx.x * 16;

  if (tid < 16) {
    int n = n0 + tid;
    int d = rs[n + 1] - rs[n];
    sScale[tid] = 1.0f / (float)(d > 1 ? d : 1);
  }
  __syncthreads();

  // stage A tiles (16 rows x 128) as float4, scaling msg by 1/deg
  for (int idx = tid; idx < 16 * 32; idx += 256) {
    int r = idx >> 5, k4 = idx & 31;
    float4 m = ((const float4*)msg)[(size_t)(n0 + r) * 32 + k4];
    float sc = sScale[r];
    m.x *= sc; m.y *= sc; m.z *= sc; m.w *= sc;
    *(float4*)&sA1[r][k4 * 4] = m;
    *(float4*)&sA2[r][k4 * 4] = ((const float4*)xin)[(size_t)(n0 + r) * 32 + k4];
  }

  const int c = tid & 127;      // output column
  const int rg = tid >> 7;      // row group (0/1), 8 rows each
  float acc[8];
#pragma unroll
  for (int i = 0; i < 8; ++i) acc[i] = 0.f;

  for (int kt = 0; kt < 128; kt += 32) {
    __syncthreads();   // previous compute done (and, first iter, nothing yet using W)
    // stage W k-tile transposed: sW[kk][c] = W[c][kt+kk]
    for (int idx = tid; idx < 1024; idx += 256) {
      int kk4 = idx & 7, cc = idx >> 3;
      float4 w = *(const float4*)&Wl[cc * 128 + kt + kk4 * 4];
      sW1[kk4 * 4 + 0][cc] = w.x; sW1[kk4 * 4 + 1][cc] = w.y;
      sW1[kk4 * 4 + 2][cc] = w.z; sW1[kk4 * 4 + 3][cc] = w.w;
      w = *(const float4*)&Wr[cc * 128 + kt + kk4 * 4];
      sW2[kk4 * 4 + 0][cc] = w.x; sW2[kk4 * 4 + 1][cc] = w.y;
      sW2[kk4 * 4 + 2][cc] = w.z; sW2[kk4 * 4 + 3][cc] = w.w;
    }
    __syncthreads();   // W (and on first iter, A) staged

#pragma unroll
    for (int kk = 0; kk < 32; kk += 4) {
      float w1[4], w2[4];
#pragma unroll
      for (int u = 0; u < 4; ++u) { w1[u] = sW1[kk + u][c]; w2[u] = sW2[kk + u][c]; }
#pragma unroll
      for (int i = 0; i < 8; ++i) {
        int r = rg * 8 + i;
        float4 a1 = *(const float4*)&sA1[r][kt + kk];
        float4 a2 = *(const float4*)&sA2[r][kt + kk];
        acc[i] += a1.x * w1[0] + a1.y * w1[1] + a1.z * w1[2] + a1.w * w1[3]
                + a2.x * w2[0] + a2.y * w2[1] + a2.z * w2[2] + a2.w * w2[3];
      }
    }
  }

  float b = bias[c];
#pragma unroll
  for (int i = 0; i < 8; ++i) {
    float o = acc[i] + b;
    if (relu) o = fmaxf(o, 0.f);
    outp[(size_t)(n0 + rg * 8 + i) * 128 + c] = o;
  }
}

extern "C" void kernel_launch(void* const* d_in, const int* in_sizes, int n_in,
                              void* d_out, int out_size, void* d_ws, size_t ws_size,
                              hipStream_t stream) {
  const float* x   = (const float*)d_in[0];
  const int*   ei  = (const int*)d_in[1];
  const float* W1l = (const float*)d_in[2];
  const float* b1l = (const float*)d_in[3];
  const float* W1r = (const float*)d_in[4];
  const float* W2l = (const float*)d_in[5];
  const float* b2l = (const float*)d_in[6];
  const float* W2r = (const float*)d_in[7];
  const int* srcp = ei;
  const int* dstp = ei + N_EDGES;

  char* ws = (char*)d_ws;
  size_t off = 0;
  auto alloc = [&](size_t bytes) {
    void* p = ws + off;
    off = (off + bytes + 255) & ~(size_t)255;
    return p;
  };
  int* deg    = (int*)alloc((size_t)N_NODES * 4);
  int* rs     = (int*)alloc((size_t)(N_NODES + 1) * 4);
  int* cursor = (int*)alloc((size_t)N_NODES * 4);
  int* eidx   = (int*)alloc((size_t)N_EDGES * 4);
  float* msg  = (float*)alloc((size_t)N_NODES * D * 4);
  float* h    = (float*)d_out;   // layer-1 activations live in d_out
  float* outp = (float*)d_out;

  hipMemsetAsync(deg, 0, (size_t)N_NODES * 4, stream);
  hipMemsetAsync(cursor, 0, (size_t)N_NODES * 4, stream);

  k_count<<<(N_EDGES + 255) / 256, 256, 0, stream>>>(dstp, deg);
  k_scan<<<1, 256, 0, stream>>>(deg, rs);
  k_fill<<<(N_EDGES + 255) / 256, 256, 0, stream>>>(srcp, dstp, rs, cursor, eidx);

  // layer 1
  k_aggregate<<<N_NODES / 4, 256, 0, stream>>>(x, rs, eidx, msg);
  k_gemm<<<N_NODES / 16, 256, 0, stream>>>(msg, x, W1l, W1r, b1l, rs, h, 1);
  // layer 2
  k_aggregate<<<N_NODES / 4, 256, 0, stream>>>(h, rs, eidx, msg);
  k_gemm<<<N_NODES / 16, 256, 0, stream>>>(msg, h, W2l, W2r, b2l, rs, outp, 0);
}

// Round 2
// 233.923 us; speedup vs baseline: 1.8914x; 1.8914x over previous
//
#include <hip/hip_runtime.h>

#define N_NODES 40000
#define N_EDGES 640000
#define D 128

typedef __attribute__((ext_vector_type(8))) short short8;
typedef __attribute__((ext_vector_type(4))) float f32x4;

__device__ __forceinline__ unsigned short f2bf(float f) {
  unsigned int u = __float_as_uint(f);
  u += 0x7fffu + ((u >> 16) & 1u);   // round-to-nearest-even
  return (unsigned short)(u >> 16);
}
__device__ __forceinline__ float bflo(unsigned int v) { return __uint_as_float(v << 16); }
__device__ __forceinline__ float bfhi(unsigned int v) { return __uint_as_float(v & 0xffff0000u); }

// ---------------- dtype converts ----------------
__global__ void k_cvt(const float* __restrict__ in, unsigned short* __restrict__ outb, int n4) {
  int i = blockIdx.x * 256 + threadIdx.x;
  if (i >= n4) return;
  float4 v = ((const float4*)in)[i];
  unsigned int lo = (unsigned int)f2bf(v.x) | ((unsigned int)f2bf(v.y) << 16);
  unsigned int hi = (unsigned int)f2bf(v.z) | ((unsigned int)f2bf(v.w) << 16);
  ((uint2*)outb)[i] = make_uint2(lo, hi);
}

__global__ void k_cvt_w(const float* __restrict__ w0, const float* __restrict__ w1,
                        const float* __restrict__ w2, const float* __restrict__ w3,
                        unsigned short* __restrict__ o0, unsigned short* __restrict__ o1,
                        unsigned short* __restrict__ o2, unsigned short* __restrict__ o3) {
  int i = blockIdx.x * 256 + threadIdx.x;      // 4 * 4096 float4 groups
  int m = i >> 12, j = i & 4095;
  const float* s = (m == 0) ? w0 : (m == 1) ? w1 : (m == 2) ? w2 : w3;
  unsigned short* o = (m == 0) ? o0 : (m == 1) ? o1 : (m == 2) ? o2 : o3;
  float4 v = ((const float4*)s)[j];
  unsigned int lo = (unsigned int)f2bf(v.x) | ((unsigned int)f2bf(v.y) << 16);
  unsigned int hi = (unsigned int)f2bf(v.z) | ((unsigned int)f2bf(v.w) << 16);
  ((uint2*)o)[j] = make_uint2(lo, hi);
}

// ---------------- CSR build ----------------
__global__ void k_count(const int* __restrict__ dst, int* __restrict__ deg) {
  int e = blockIdx.x * 256 + threadIdx.x;
  if (e < N_EDGES) atomicAdd(&deg[dst[e]], 1);
}

__global__ void k_scan(const int* __restrict__ deg, int* __restrict__ rs) {
  __shared__ int wsum[4];
  __shared__ int carry_s;
  const int tid = threadIdx.x;
  const int lane = tid & 63;
  const int wid = tid >> 6;
  if (tid == 0) carry_s = 0;
  __syncthreads();
  const int CH = 256 * 16;
  for (int base = 0; base < N_NODES; base += CH) {
    int v[16];
    int i0 = base + tid * 16;
    int s = 0;
#pragma unroll
    for (int j = 0; j < 16; ++j) {
      int idx = i0 + j;
      v[j] = (idx < N_NODES) ? deg[idx] : 0;
      s += v[j];
    }
    int sc = s;
#pragma unroll
    for (int d = 1; d < 64; d <<= 1) {
      int t = __shfl_up(sc, d, 64);
      if (lane >= d) sc += t;
    }
    if (lane == 63) wsum[wid] = sc;
    __syncthreads();
    int wpre = 0;
    for (int w = 0; w < wid; ++w) wpre += wsum[w];
    int run = carry_s + wpre + (sc - s);
#pragma unroll
    for (int j = 0; j < 16; ++j) {
      int idx = i0 + j;
      if (idx < N_NODES) rs[idx] = run;
      run += v[j];
    }
    __syncthreads();
    if (tid == 0) carry_s += wsum[0] + wsum[1] + wsum[2] + wsum[3];
    __syncthreads();
  }
  if (tid == 0) rs[N_NODES] = carry_s;
}

__global__ void k_fill(const int* __restrict__ src, const int* __restrict__ dst,
                       const int* __restrict__ rs, int* __restrict__ cursor,
                       int* __restrict__ eidx) {
  int e = blockIdx.x * 256 + threadIdx.x;
  if (e < N_EDGES) {
    int d = dst[e];
    int pos = atomicAdd(&cursor[d], 1);
    eidx[rs[d] + pos] = src[e];
  }
}

// ---------------- aggregation: meanb[n] = bf16( (1/deg) * sum feat[src] ) ----------------
__global__ void k_agg(const unsigned int* __restrict__ feat2, const int* __restrict__ rs,
                      const int* __restrict__ eidx, unsigned int* __restrict__ mean2) {
  int node = blockIdx.x * 4 + (threadIdx.x >> 6);
  int lane = threadIdx.x & 63;
  if (node >= N_NODES) return;
  int beg = rs[node], end = rs[node + 1];
  float ax = 0.f, ay = 0.f;
  int e = beg;
  for (; e + 4 <= end; e += 4) {
    int s0 = eidx[e], s1 = eidx[e + 1], s2 = eidx[e + 2], s3 = eidx[e + 3];
    unsigned int v0 = feat2[(size_t)s0 * 64 + lane];
    unsigned int v1 = feat2[(size_t)s1 * 64 + lane];
    unsigned int v2 = feat2[(size_t)s2 * 64 + lane];
    unsigned int v3 = feat2[(size_t)s3 * 64 + lane];
    ax += bflo(v0) + bflo(v1) + bflo(v2) + bflo(v3);
    ay += bfhi(v0) + bfhi(v1) + bfhi(v2) + bfhi(v3);
  }
  for (; e < end; ++e) {
    unsigned int v = feat2[(size_t)eidx[e] * 64 + lane];
    ax += bflo(v);
    ay += bfhi(v);
  }
  int d = end - beg;
  float inv = 1.0f / (float)(d > 1 ? d : 1);
  ax *= inv; ay *= inv;
  mean2[(size_t)node * 64 + lane] = (unsigned int)f2bf(ax) | ((unsigned int)f2bf(ay) << 16);
}

// ---------------- fused dual bf16-MFMA GEMM: out = Al@Wl^T + b + Ar@Wr^T ----------------
__global__ __launch_bounds__(256) void k_gemm(
    const unsigned short* __restrict__ Al, const unsigned short* __restrict__ Ar,
    const unsigned short* __restrict__ Wl, const unsigned short* __restrict__ Wr,
    const float* __restrict__ bias,
    unsigned short* __restrict__ out_bf, float* __restrict__ out_f, int relu_bf16) {
  const int tid = threadIdx.x;
  const int wid = tid >> 6, lane = tid & 63;
  const int m0 = blockIdx.x * 64 + wid * 16;
  const int ml = lane & 15;      // row within M-tile / col within N-tile
  const int kg = lane >> 4;      // k-group of 8
  const unsigned short* al_p = Al + (size_t)(m0 + ml) * 128 + kg * 8;
  const unsigned short* ar_p = Ar + (size_t)(m0 + ml) * 128 + kg * 8;
  const unsigned short* wl_p = Wl + (size_t)ml * 128 + kg * 8;
  const unsigned short* wr_p = Wr + (size_t)ml * 128 + kg * 8;

  f32x4 acc[8];
#pragma unroll
  for (int nt = 0; nt < 8; ++nt) acc[nt] = 0;

#pragma unroll
  for (int kt = 0; kt < 4; ++kt) {
    short8 a_l = *(const short8*)(al_p + kt * 32);
    short8 a_r = *(const short8*)(ar_p + kt * 32);
#pragma unroll
    for (int nt = 0; nt < 8; ++nt) {
      short8 b_l = *(const short8*)(wl_p + nt * 2048 + kt * 32);
      short8 b_r = *(const short8*)(wr_p + nt * 2048 + kt * 32);
      acc[nt] = __builtin_amdgcn_mfma_f32_16x16x32_bf16(a_l, b_l, acc[nt], 0, 0, 0);
      acc[nt] = __builtin_amdgcn_mfma_f32_16x16x32_bf16(a_r, b_r, acc[nt], 0, 0, 0);
    }
  }

  const int orow = m0 + (lane >> 4) * 4;   // + r
#pragma unroll
  for (int nt = 0; nt < 8; ++nt) {
    int col = nt * 16 + ml;
    float b = bias[col];
#pragma unroll
    for (int r = 0; r < 4; ++r) {
      float o = acc[nt][r] + b;
      if (relu_bf16) {
        o = fmaxf(o, 0.f);
        out_bf[(size_t)(orow + r) * 128 + col] = f2bf(o);
      } else {
        out_f[(size_t)(orow + r) * 128 + col] = o;
      }
    }
  }
}

extern "C" void kernel_launch(void* const* d_in, const int* in_sizes, int n_in,
                              void* d_out, int out_size, void* d_ws, size_t ws_size,
                              hipStream_t stream) {
  const float* x   = (const float*)d_in[0];
  const int*   ei  = (const int*)d_in[1];
  const float* W1l = (const float*)d_in[2];
  const float* b1l = (const float*)d_in[3];
  const float* W1r = (const float*)d_in[4];
  const float* W2l = (const float*)d_in[5];
  const float* b2l = (const float*)d_in[6];
  const float* W2r = (const float*)d_in[7];
  const int* srcp = ei;
  const int* dstp = ei + N_EDGES;

  char* ws = (char*)d_ws;
  size_t off = 0;
  auto alloc = [&](size_t bytes) {
    void* p = ws + off;
    off = (off + bytes + 255) & ~(size_t)255;
    return p;
  };
  int* deg    = (int*)alloc((size_t)N_NODES * 4);
  int* rs     = (int*)alloc((size_t)(N_NODES + 1) * 4);
  int* cursor = (int*)alloc((size_t)N_NODES * 4);
  int* eidx   = (int*)alloc((size_t)N_EDGES * 4);
  unsigned short* w1lb = (unsigned short*)alloc((size_t)D * D * 2);
  unsigned short* w1rb = (unsigned short*)alloc((size_t)D * D * 2);
  unsigned short* w2lb = (unsigned short*)alloc((size_t)D * D * 2);
  unsigned short* w2rb = (unsigned short*)alloc((size_t)D * D * 2);
  unsigned short* bufA = (unsigned short*)alloc((size_t)N_NODES * D * 2); // xb, then mean2
  unsigned short* bufB = (unsigned short*)alloc((size_t)N_NODES * D * 2); // mean1, then hb

  hipMemsetAsync(deg, 0, (size_t)N_NODES * 4, stream);
  hipMemsetAsync(cursor, 0, (size_t)N_NODES * 4, stream);

  // converts
  k_cvt<<<(N_NODES * D / 4 + 255) / 256, 256, 0, stream>>>(x, bufA, N_NODES * D / 4);
  k_cvt_w<<<64, 256, 0, stream>>>(W1l, W1r, W2l, W2r, w1lb, w1rb, w2lb, w2rb);

  // CSR
  k_count<<<(N_EDGES + 255) / 256, 256, 0, stream>>>(dstp, deg);
  k_scan<<<1, 256, 0, stream>>>(deg, rs);
  k_fill<<<(N_EDGES + 255) / 256, 256, 0, stream>>>(srcp, dstp, rs, cursor, eidx);

  // layer 1: mean1 = agg(xb) -> bufB ; h(bf16) = relu(mean1@W1l^T + b + xb@W1r^T) -> bufB
  k_agg<<<N_NODES / 4, 256, 0, stream>>>((const unsigned int*)bufA, rs, eidx, (unsigned int*)bufB);
  k_gemm<<<N_NODES / 64, 256, 0, stream>>>(bufB, bufA, w1lb, w1rb, b1l, bufB, nullptr, 1);

  // layer 2: mean2 = agg(hb) -> bufA ; out(fp32) = mean2@W2l^T + b + hb@W2r^T -> d_out
  k_agg<<<N_NODES / 4, 256, 0, stream>>>((const unsigned int*)bufB, rs, eidx, (unsigned int*)bufA);
  k_gemm<<<N_NODES / 64, 256, 0, stream>>>(bufA, bufB, w2lb, w2rb, b2l, nullptr, (float*)d_out, 0);
}